// Round 4
// baseline (141.314 us; speedup 1.0000x reference)
//
#include <hip/hip_runtime.h>

#define NTOK 64
#define HEADS 8

typedef __attribute__((ext_vector_type(4))) float f32x4;
typedef __attribute__((ext_vector_type(2))) unsigned int u32x2;
typedef __attribute__((ext_vector_type(8))) short bf16x8;

__device__ float g_bias225[225 * 8];   // overwritten fully every launch (deterministic)

__device__ __forceinline__ unsigned int f2bf(float f) {
    unsigned int u = __float_as_uint(f);
    u += 0x7FFFu + ((u >> 16) & 1u);   // round-to-nearest-even bf16
    return u >> 16;
}

// Stage 1: MLP over the 225 distinct relative positions. One wave per pair.
__global__ __launch_bounds__(64) void mlp_pairs_kernel(
    const float* __restrict__ w1, const float* __restrict__ b1,
    const float* __restrict__ w2, const float* __restrict__ b2)
{
    int pair = blockIdx.x;
    int lane = threadIdx.x;
    int dy = pair / 15 - 7;
    int dx = pair % 15 - 7;
    float fy = copysignf(log1pf(fabsf((float)dy)), (float)dy);
    float fx = copysignf(log1pf(fabsf((float)dx)), (float)dx);
    int h = lane & 7;
    int j0 = lane >> 3;
    float acc = 0.0f;
    #pragma unroll 4
    for (int i = 0; i < 32; ++i) {
        int j = j0 + 8 * i;
        float t = fy * w1[j] + fx * w1[256 + j] + b1[j];
        float ge = 0.5f * t * (1.0f + erff(t * 0.70710678118654752f)); // exact GELU
        acc = fmaf(ge, w2[j * HEADS + h], acc);
    }
    acc += __shfl_xor(acc, 8, 64);
    acc += __shfl_xor(acc, 16, 64);
    acc += __shfl_xor(acc, 32, 64);
    if (lane < 8)
        g_bias225[pair * 8 + lane] = (acc + b2[lane]) * 1.44269504088896341f; // fold log2(e)
}

// Stage 2: scatter bias225 -> fragment-layout table
// bias_ws[h][mt][nt][lane][r] = log2e * bias[h][n][m],
//   m = mt*16 + (lane>>4)*4 + r (S^T C-frag row), n = nt*16 + (lane&15) (col)
__global__ __launch_bounds__(256) void bias_scatter_kernel(float* __restrict__ bias_ws)
{
    int idx = blockIdx.x * 256 + threadIdx.x;   // 32768 total
    int r  = idx & 3;
    int l  = (idx >> 2) & 63;
    int nt = (idx >> 8) & 3;
    int mt = (idx >> 10) & 3;
    int h  = idx >> 12;
    int n = nt * 16 + (l & 15);
    int m = mt * 16 + (l >> 4) * 4 + r;
    int pair = ((n >> 3) - (m >> 3) + 7) * 15 + ((n & 7) - (m & 7) + 7);
    bias_ws[idx] = g_bias225[pair * 8 + h];
}

// One wave per (window b, head h). 4 waves/block, fully independent (no barrier).
// All global loads hoisted to wave start; per-strip Q+bias prefetch; no max-subtract.
__global__ __launch_bounds__(256, 3) void win_attn_kernel(
    const float* __restrict__ qkv,
    const float* __restrict__ bias_ws,
    float* __restrict__ out)
{
    __shared__ __align__(16) unsigned short p_lds[4][2][16][72]; // dbuf wave-private slices
    const int w = threadIdx.x >> 6;
    const int l = threadIdx.x & 63;
    const int c = l & 15;
    const int g = l >> 4;
    const int W = blockIdx.x * 4 + w;
    const int h = W & 7;
    const int b = W >> 3;
    const float* base = qkv + (size_t)b * (NTOK * 768) + h * 32;
    const float QS = 0.176776695296636893f * 1.44269504088896341f; // scale * log2(e)

    // ---- Phase 0: issue ALL global loads (24 KB in flight) ----
    f32x4 kraw[4][2];
    #pragma unroll
    for (int t = 0; t < 4; ++t) {
        const float* pk = base + (size_t)(t * 16 + c) * 768 + 256 + g * 8;
        kraw[t][0] = *(const f32x4*)(pk);
        kraw[t][1] = *(const f32x4*)(pk + 4);
    }
    float vraw[2][2][8];
    {
        const float* vb = base + 512;
        #pragma unroll
        for (int ks = 0; ks < 2; ++ks)
            #pragma unroll
            for (int dt = 0; dt < 2; ++dt)
                #pragma unroll
                for (int j = 0; j < 8; ++j)
                    vraw[ks][dt][j] = vb[(size_t)(ks * 32 + g * 8 + j) * 768 + dt * 16 + c];
    }
    f32x4 qraw0, qraw1;
    {
        const float* pq = base + (size_t)c * 768 + g * 8;   // strip 0
        qraw0 = *(const f32x4*)(pq);
        qraw1 = *(const f32x4*)(pq + 4);
    }
    const f32x4* bias_base = (const f32x4*)bias_ws + (size_t)h * 1024 + l;
    f32x4 bias_cur[4];
    #pragma unroll
    for (int mt = 0; mt < 4; ++mt)
        bias_cur[mt] = bias_base[mt * 256];                 // nt=0

    // ---- convert K, V (overlaps load returns via fine-grained vmcnt) ----
    bf16x8 kf[4];
    #pragma unroll
    for (int t = 0; t < 4; ++t) {
        bf16x8 k;
        #pragma unroll
        for (int j = 0; j < 4; ++j) {
            k[j]     = (short)f2bf(kraw[t][0][j]);
            k[4 + j] = (short)f2bf(kraw[t][1][j]);
        }
        kf[t] = k;
    }
    bf16x8 vf[2][2];
    #pragma unroll
    for (int ks = 0; ks < 2; ++ks)
        #pragma unroll
        for (int dt = 0; dt < 2; ++dt) {
            bf16x8 v;
            #pragma unroll
            for (int j = 0; j < 8; ++j)
                v[j] = (short)f2bf(vraw[ks][dt][j]);
            vf[ks][dt] = v;
        }

    unsigned short (*Pb)[16][72] = p_lds[w];
    float* ob = out + (size_t)b * (NTOK * 256) + h * 32;

    // ---- strip loop over n (nt): S^T strip -> exp2 -> P -> O^T strip ----
    #pragma unroll
    for (int nt = 0; nt < 4; ++nt) {
        bf16x8 qf;
        #pragma unroll
        for (int j = 0; j < 4; ++j) {
            qf[j]     = (short)f2bf(qraw0[j] * QS);
            qf[4 + j] = (short)f2bf(qraw1[j] * QS);
        }

        // S^T strip = K.Q^T seeded directly with prefetched bias frags
        f32x4 acc[4];
        #pragma unroll
        for (int mt = 0; mt < 4; ++mt)
            acc[mt] = __builtin_amdgcn_mfma_f32_16x16x32_bf16(kf[mt], qf, bias_cur[mt], 0, 0, 0);

        // prefetch next strip's Q + bias while MFMAs run
        if (nt < 3) {
            const float* pq = base + (size_t)((nt + 1) * 16 + c) * 768 + g * 8;
            qraw0 = *(const f32x4*)(pq);
            qraw1 = *(const f32x4*)(pq + 4);
            #pragma unroll
            for (int mt = 0; mt < 4; ++mt)
                bias_cur[mt] = bias_base[mt * 256 + (nt + 1) * 64];
        }

        // softmax numerators, NO max-subtract (scores bounded ~|12| in log2 units -> f32 safe;
        // normalization makes it mathematically identical to the shifted form)
        float s = 0.0f;
        #pragma unroll
        for (int mt = 0; mt < 4; ++mt)
            #pragma unroll
            for (int r = 0; r < 4; ++r) {
                float p = __builtin_amdgcn_exp2f(acc[mt][r]);
                acc[mt][r] = p;
                s += p;
            }

        // P strip (bf16, [n][m]) -> LDS (packed b64 writes, double-buffered)
        unsigned short (*P)[72] = Pb[nt & 1];
        #pragma unroll
        for (int mt = 0; mt < 4; ++mt) {
            unsigned int w0 = f2bf(acc[mt][0]) | (f2bf(acc[mt][1]) << 16);
            unsigned int w1 = f2bf(acc[mt][2]) | (f2bf(acc[mt][3]) << 16);
            *(u32x2*)(&P[c][mt * 16 + g * 4]) = (u32x2){w0, w1};
        }

        // cross-lane sum finish + rcp: off critical path, overlaps PV below
        s += __shfl_xor(s, 16, 64);
        s += __shfl_xor(s, 32, 64);
        float iv = __builtin_amdgcn_rcpf(s);

        // O^T strip = V^T . P^T
        f32x4 o[2];
        o[0] = (f32x4){0.f, 0.f, 0.f, 0.f};
        o[1] = (f32x4){0.f, 0.f, 0.f, 0.f};
        #pragma unroll
        for (int ks = 0; ks < 2; ++ks) {
            bf16x8 pb = *(const bf16x8*)(&P[c][ks * 32 + g * 8]);
            #pragma unroll
            for (int dt = 0; dt < 2; ++dt)
                o[dt] = __builtin_amdgcn_mfma_f32_16x16x32_bf16(vf[ks][dt], pb, o[dt], 0, 0, 0);
        }

        // normalize + store (4 consecutive d per reg -> dwordx4)
        #pragma unroll
        for (int dt = 0; dt < 2; ++dt) {
            f32x4 val;
            #pragma unroll
            for (int r = 0; r < 4; ++r)
                val[r] = o[dt][r] * iv;
            *(f32x4*)(ob + (size_t)(nt * 16 + c) * 256 + dt * 16 + g * 4) = val;
        }
    }
}

extern "C" void kernel_launch(void* const* d_in, const int* in_sizes, int n_in,
                              void* d_out, int out_size, void* d_ws, size_t ws_size,
                              hipStream_t stream) {
    const float* qkv = (const float*)d_in[0];
    const float* w1  = (const float*)d_in[1];
    const float* b1  = (const float*)d_in[2];
    const float* w2  = (const float*)d_in[3];
    const float* b2  = (const float*)d_in[4];
    float* bias_ws = (float*)d_ws;   // 32768 floats = 128 KiB (proven size)

    mlp_pairs_kernel<<<225, 64, 0, stream>>>(w1, b1, w2, b2);
    bias_scatter_kernel<<<128, 256, 0, stream>>>(bias_ws);

    int B = in_sizes[0] / 49152;   // windows
    win_attn_kernel<<<B * 2, 256, 0, stream>>>(qkv, bias_ws, (float*)d_out);
}

// Round 7
// 138.463 us; speedup vs baseline: 1.0206x; 1.0206x over previous
//
#include <hip/hip_runtime.h>
#include <hip/hip_bf16.h>
#include <string.h>

#define NTOK 64
#define HEADS 8

typedef __attribute__((ext_vector_type(4))) float f32x4;
typedef __attribute__((ext_vector_type(2))) unsigned int u32x2;
typedef __attribute__((ext_vector_type(4))) unsigned int u32x4;
typedef __attribute__((ext_vector_type(8))) short bf16x8;

__device__ float g_bias225[225 * 8];   // overwritten fully every launch (deterministic)

// packed f32x2 -> bf16x2 (RNE) -- compiler emits v_cvt_pk_bf16_f32
__device__ __forceinline__ unsigned int cvt2(float a, float b) {
    __hip_bfloat162 h = __float22bfloat162_rn(float2{a, b});
    unsigned int r;
    memcpy(&r, &h, 4);
    return r;
}

// Stage 1: MLP over the 225 distinct relative positions. One wave per pair.
__global__ __launch_bounds__(64) void mlp_pairs_kernel(
    const float* __restrict__ w1, const float* __restrict__ b1,
    const float* __restrict__ w2, const float* __restrict__ b2)
{
    int pair = blockIdx.x;
    int lane = threadIdx.x;
    int dy = pair / 15 - 7;
    int dx = pair % 15 - 7;
    float fy = copysignf(log1pf(fabsf((float)dy)), (float)dy);
    float fx = copysignf(log1pf(fabsf((float)dx)), (float)dx);
    int h = lane & 7;
    int j0 = lane >> 3;
    float acc = 0.0f;
    #pragma unroll 4
    for (int i = 0; i < 32; ++i) {
        int j = j0 + 8 * i;
        float t = fy * w1[j] + fx * w1[256 + j] + b1[j];
        float ge = 0.5f * t * (1.0f + erff(t * 0.70710678118654752f)); // exact GELU
        acc = fmaf(ge, w2[j * HEADS + h], acc);
    }
    acc += __shfl_xor(acc, 8, 64);
    acc += __shfl_xor(acc, 16, 64);
    acc += __shfl_xor(acc, 32, 64);
    if (lane < 8)
        g_bias225[pair * 8 + lane] = (acc + b2[lane]) * 1.44269504088896341f; // fold log2(e)
}

// Stage 2: scatter bias225 -> fragment-layout table
// bias_ws[h][mt][nt][lane][r] = log2e * bias[h][n][m],
//   m = mt*16 + (lane>>4)*4 + r (S^T C-frag row), n = nt*16 + (lane&15) (col)
__global__ __launch_bounds__(256) void bias_scatter_kernel(float* __restrict__ bias_ws)
{
    int idx = blockIdx.x * 256 + threadIdx.x;   // 32768 total
    int r  = idx & 3;
    int l  = (idx >> 2) & 63;
    int nt = (idx >> 8) & 3;
    int mt = (idx >> 10) & 3;
    int h  = idx >> 12;
    int n = nt * 16 + (l & 15);
    int m = mt * 16 + (l >> 4) * 4 + r;
    int pair = ((n >> 3) - (m >> 3) + 7) * 15 + ((n & 7) - (m & 7) + 7);
    bias_ws[idx] = g_bias225[pair * 8 + h];
}

// One wave per (window b, head h). 4 waves/block, fully independent (no barrier).
// V staged via coalesced loads + LDS transpose-bounce (separate region, fenced);
// P in its own double-buffered region. Packed cvt throughout.
__global__ __launch_bounds__(256, 4) void win_attn_kernel(
    const float* __restrict__ qkv,
    const float* __restrict__ bias_ws,
    float* __restrict__ out)
{
    // per-wave: V bf16 [64][34] (2176 us), P dbuf 2x[16][72] (2304 us) -- disjoint regions
    __shared__ __align__(16) unsigned short lds_v[4][2176];
    __shared__ __align__(16) unsigned short lds_p[4][2][16][72];
    const int w = threadIdx.x >> 6;
    const int l = threadIdx.x & 63;
    const int c = l & 15;
    const int g = l >> 4;
    const int W = blockIdx.x * 4 + w;
    const int h = W & 7;
    const int b = W >> 3;
    const float* base = qkv + (size_t)b * (NTOK * 768) + h * 32;
    const float QS = 0.176776695296636893f * 1.44269504088896341f; // scale * log2(e)
    unsigned short* vbuf = lds_v[w];

    // ---- stage V: 8 coalesced dwordx4 (full cachelines) -> packed cvt -> LDS [64][34] ----
    {
        const int sq = l >> 2;          // row within 16-row group
        const int ss = l & 3;           // 8-float chunk within row
        #pragma unroll
        for (int k = 0; k < 4; ++k) {
            int m = k * 16 + sq;
            const float* p = base + (size_t)m * 768 + 512 + ss * 8;
            f32x4 a0 = *(const f32x4*)(p);
            f32x4 a1 = *(const f32x4*)(p + 4);
            unsigned int* dst = (unsigned int*)(vbuf + m * 34 + ss * 8); // byte m*68+ss*16, 4B-aligned
            dst[0] = cvt2(a0[0], a0[1]);
            dst[1] = cvt2(a0[2], a0[3]);
            dst[2] = cvt2(a1[0], a1[1]);
            dst[3] = cvt2(a1[2], a1[3]);
        }
    }

    // ---- K fragments direct from global (A-frag: own-row = c, k-chunk = g*8) ----
    bf16x8 kf[4];
    #pragma unroll
    for (int t = 0; t < 4; ++t) {
        const float* pk = base + (size_t)(t * 16 + c) * 768 + 256 + g * 8;
        f32x4 y0 = *(const f32x4*)(pk);
        f32x4 y1 = *(const f32x4*)(pk + 4);
        u32x4 kk = {cvt2(y0[0], y0[1]), cvt2(y0[2], y0[3]),
                    cvt2(y1[0], y1[1]), cvt2(y1[2], y1[3])};
        bf16x8 k;
        memcpy(&k, &kk, 16);
        kf[t] = k;
    }

    // order: all lanes' V ds_writes complete before cross-lane ds_reads below
    __threadfence_block();

    // ---- read V^T A-frags from LDS (stride 17 dwords -> conflict-free u16 reads) ----
    bf16x8 vf[2][2];
    #pragma unroll
    for (int ks = 0; ks < 2; ++ks)
        #pragma unroll
        for (int dt = 0; dt < 2; ++dt) {
            bf16x8 v;
            #pragma unroll
            for (int j = 0; j < 8; ++j)
                v[j] = (short)vbuf[(ks * 32 + g * 8 + j) * 34 + dt * 16 + c];
            vf[ks][dt] = v;
        }

    float* ob = out + (size_t)b * (NTOK * 256) + h * 32;

    // ---- strip loop over n (nt): S^T strip -> exp2 -> P -> O^T strip ----
    #pragma unroll
    for (int nt = 0; nt < 4; ++nt) {
        // Q strip fragment (B-frag: own-col n = c, k-chunk g*8)
        bf16x8 qf;
        {
            const float* pq = base + (size_t)(nt * 16 + c) * 768 + g * 8;
            f32x4 x0 = *(const f32x4*)(pq);
            f32x4 x1 = *(const f32x4*)(pq + 4);
            u32x4 qq = {cvt2(x0[0] * QS, x0[1] * QS), cvt2(x0[2] * QS, x0[3] * QS),
                        cvt2(x1[0] * QS, x1[1] * QS), cvt2(x1[2] * QS, x1[3] * QS)};
            memcpy(&qf, &qq, 16);
        }

        // S^T strip = K.Q^T seeded with bias frags (C-operand)
        f32x4 acc[4];
        {
            const f32x4* bw = (const f32x4*)(bias_ws) + ((size_t)h * 16 + nt) * 64 + l;
            #pragma unroll
            for (int mt = 0; mt < 4; ++mt)
                acc[mt] = bw[mt * 256];
        }
        #pragma unroll
        for (int mt = 0; mt < 4; ++mt)
            acc[mt] = __builtin_amdgcn_mfma_f32_16x16x32_bf16(kf[mt], qf, acc[mt], 0, 0, 0);

        // softmax numerators, no max-subtract (scores bounded in log2 units; f32-safe;
        // identical after normalization)
        float s = 0.0f;
        #pragma unroll
        for (int mt = 0; mt < 4; ++mt)
            #pragma unroll
            for (int r = 0; r < 4; ++r) {
                float p = __builtin_amdgcn_exp2f(acc[mt][r]);
                acc[mt][r] = p;
                s += p;
            }

        // P strip (bf16, [n][m]) -> LDS (packed cvt + b64 writes, double-buffered)
        unsigned short (*P)[72] = lds_p[w][nt & 1];
        #pragma unroll
        for (int mt = 0; mt < 4; ++mt) {
            unsigned int w0 = cvt2(acc[mt][0], acc[mt][1]);
            unsigned int w1 = cvt2(acc[mt][2], acc[mt][3]);
            *(u32x2*)(&P[c][mt * 16 + g * 4]) = (u32x2){w0, w1};
        }

        // cross-lane sum finish + rcp (overlaps the fence's drain)
        s += __shfl_xor(s, 16, 64);
        s += __shfl_xor(s, 32, 64);
        float iv = __builtin_amdgcn_rcpf(s);

        // order: P ds_writes visible before cross-lane ds_reads
        __threadfence_block();

        // O^T strip = V^T . P^T
        f32x4 o[2];
        o[0] = (f32x4){0.f, 0.f, 0.f, 0.f};
        o[1] = (f32x4){0.f, 0.f, 0.f, 0.f};
        #pragma unroll
        for (int ks = 0; ks < 2; ++ks) {
            bf16x8 pb = *(const bf16x8*)(&P[c][ks * 32 + g * 8]);
            #pragma unroll
            for (int dt = 0; dt < 2; ++dt)
                o[dt] = __builtin_amdgcn_mfma_f32_16x16x32_bf16(vf[ks][dt], pb, o[dt], 0, 0, 0);
        }

        // normalize + store (4 consecutive d per reg -> dwordx4)
        #pragma unroll
        for (int dt = 0; dt < 2; ++dt) {
            f32x4 val;
            #pragma unroll
            for (int r = 0; r < 4; ++r)
                val[r] = o[dt][r] * iv;
            *(f32x4*)(ob + (size_t)(nt * 16 + c) * 256 + dt * 16 + g * 4) = val;
        }
    }
}

extern "C" void kernel_launch(void* const* d_in, const int* in_sizes, int n_in,
                              void* d_out, int out_size, void* d_ws, size_t ws_size,
                              hipStream_t stream) {
    const float* qkv = (const float*)d_in[0];
    const float* w1  = (const float*)d_in[1];
    const float* b1  = (const float*)d_in[2];
    const float* w2  = (const float*)d_in[3];
    const float* b2  = (const float*)d_in[4];
    float* bias_ws = (float*)d_ws;   // 32768 floats = 128 KiB (proven size)

    mlp_pairs_kernel<<<225, 64, 0, stream>>>(w1, b1, w2, b2);
    bias_scatter_kernel<<<128, 256, 0, stream>>>(bias_ws);

    int B = in_sizes[0] / 49152;   // windows
    win_attn_kernel<<<B * 2, 256, 0, stream>>>(qkv, bias_ws, (float*)d_out);
}